// Round 5
// baseline (41.621 us; speedup 1.0000x reference)
//
#include <hip/hip_runtime.h>
#include <hip/hip_bf16.h>

// Problem constants (B,T,H,W,D = 32,16,32,32,64)
#define B_   32
#define T_   16
#define H_   32
#define W_   32
#define D_   64
#define N_   16384          // T*H*W
#define BLK  256
#define BLK_S 1024          // select block size (16 waves)
#define SEG_  8             // phase-A blocks per row
#define KPT_A 2             // keys per thread in phase A (N_/SEG_/BLK_S)
#define KPT_S 16            // keys per thread in phase B (N_/BLK_S)
#define LOSS_BLOCKS 2048
#define CAP 2048            // candidate list cap (level-2 expected ~2-30)
#define NBIN 2048

// ---------------------------------------------------------------------------
// K1a: wide phase — 256 blocks (8 per row). Each computes 2048 keys, writes
// them to the output region (overwritten by the mask in K1b), builds a
// private LDS histogram (top 11 key bits) and dumps it to ws WITHOUT global
// atomics.
// ---------------------------------------------------------------------------
__global__ __launch_bounds__(BLK_S, 1) void select_a_kernel(
    const float* __restrict__ u_g,
    const float* __restrict__ logp_t,
    const float* __restrict__ logp_h,
    const float* __restrict__ logp_w,
    unsigned* __restrict__ keys_out,    // (out+1) region, [B_][N_]
    unsigned* __restrict__ hist_out)    // ws, [B_*SEG_][NBIN]
{
    const int ba  = blockIdx.x;          // 0..255
    const int b   = ba >> 3;
    const int sg  = ba & 7;
    const int tid = threadIdx.x;

    __shared__ float s_lt[T_], s_lh[H_], s_lw[W_];
    __shared__ unsigned s_hist[NBIN];

    if (tid < T_) s_lt[tid] = logp_t[b*T_ + tid];
    if (tid < H_) s_lh[tid] = logp_h[b*H_ + tid];
    if (tid < W_) s_lw[tid] = logp_w[b*W_ + tid];
    s_hist[tid]        = 0u;
    s_hist[tid + 1024] = 0u;
    __syncthreads();

    // NUMERICS LOCKED: stepwise fp32 -logf(-logf(u)), add order (lt+lh)+lw
    // matched the np reference exactly (absmax 0.0). Do not alter.
#pragma unroll
    for (int i = 0; i < KPT_A; ++i) {
        int   n = sg*(N_/SEG_) + i*BLK_S + tid;
        float u = u_g[b*N_ + n];
        float g = -logf(-logf(u));
        int t = n >> 10;            // / (H_*W_)
        int h = (n >> 5) & 31;
        int w = n & 31;
        float wsv = g + ((s_lt[t] + s_lh[h]) + s_lw[w]);
        unsigned bits = __float_as_uint(wsv);
        unsigned key  = (bits & 0x80000000u) ? ~bits : (bits | 0x80000000u);
        keys_out[b*N_ + n] = key;
        atomicAdd(&s_hist[key >> 21], 1u);
    }
    __syncthreads();

    hist_out[ba*NBIN + tid]        = s_hist[tid];
    hist_out[ba*NBIN + tid + 1024] = s_hist[tid + 1024];
}

// ---------------------------------------------------------------------------
// K1b: narrow phase — 32 blocks (1 per row). Sums the 8 sub-histograms IN
// REGISTERS, suffix-scans to find the k-th bucket, level-2 refine + exact
// threshold + tie logic (proven R6 code), writes the visible mask over the
// key buffer, AND (R9) compacts the masked token indices over its OWN
// consumed histogram region (8*2048*4B == 16384*4B exactly; hist reads all
// complete before B1, writes happen after B7, each block touches only its
// row's region -> no hazard, no extra ws). Per-row masked count = N_-k.
// ---------------------------------------------------------------------------
__global__ __launch_bounds__(BLK_S, 1) void select_b_kernel(
    unsigned* keybuf,                   // (out+1): keys in, mask (float bits) out
    unsigned* histlist,                 // ws: sub-hists in, masked-token list out
    const float* __restrict__ u_k,
    double* __restrict__ invrc,         // ws[0..31] = 1/rc_b
    unsigned* __restrict__ cnt_out)     // ws: [B_] masked counts
{
    const int b    = blockIdx.x;
    const int tid  = threadIdx.x;
    const int lane = tid & 63;
    const int wv   = tid >> 6;       // 0..15

    __shared__ unsigned s_hist2[NBIN];
    __shared__ unsigned s_wsum[16];
    __shared__ int s_bucket, s_above, s_cnt;
    __shared__ unsigned s_thr;
    __shared__ int s_cgt, s_ceq;
    __shared__ unsigned long long s_list[CAP];  // (key<<32)|index

    s_hist2[tid]        = 0u;
    s_hist2[tid + 1024] = 0u;
    if (tid == 0) s_cnt = 0;

    // ---- sum the 8 sub-histograms for bins {2t, 2t+1} (registers only) ----
    unsigned h0 = 0, h1 = 0;
    {
        const uint2* hb2 = (const uint2*)(histlist + (size_t)b*SEG_*NBIN);
#pragma unroll
        for (int j = 0; j < SEG_; ++j) {
            uint2 v = hb2[j*(NBIN/2) + tid];
            h0 += v.x; h1 += v.y;
        }
    }

    // ---- reload this row's keys (written by phase A; cache-resident) ----
    unsigned keys[KPT_S];
#pragma unroll
    for (int i = 0; i < KPT_S; ++i)
        keys[i] = keybuf[b*N_ + i*BLK_S + tid];

    // ---- k for this row (np.linspace + fp32 mod/trunc semantics) ----
    float u0    = u_k[0];
    float strat = (b == B_-1) ? 1.0f : (float)((double)b * (1.0/31.0));
    float rate  = fmodf(u0 + strat, 1.0f);
    int   k     = (int)(16384.0f * rate);
    k = k < 1 ? 1 : (k > N_-1 ? N_-1 : k);

    // ================= level-1 suffix scan: find 11-bit bucket =============
    {
        const unsigned p = h0 + h1;
        unsigned x = p;                     // inclusive suffix sum in wave
#pragma unroll
        for (int off = 1; off < 64; off <<= 1) {
            unsigned y = __shfl_down(x, off);
            if (lane + off < 64) x += y;
        }
        if (lane == 0) s_wsum[wv] = x;
        __syncthreads();                                       // B1
        unsigned wsuf = 0;
#pragma unroll
        for (int w2 = 0; w2 < 16; ++w2) wsuf += (w2 > wv) ? s_wsum[w2] : 0u;
        const unsigned sufExcl = (x - p) + wsuf;   // keys in bins > 2t+1
        const unsigned ku = (unsigned)k;
        const unsigned a1 = sufExcl;               // above bin 2t+1
        const unsigned a0 = sufExcl + h1;          // above bin 2t
        if (a1 < ku && ku <= a1 + h1) { s_bucket = 2*tid + 1; s_above = (int)a1; }
        if (a0 < ku && ku <= a0 + h0) { s_bucket = 2*tid;     s_above = (int)a0; }
        __syncthreads();                                       // B2
    }

    const int bucket = s_bucket;        // 11-bit prefix of the k-th key
    const int above  = s_above;         // # keys in higher buckets
    const int need   = k - above;       // rank of k-th key within bucket

    // ================= level-2: histogram bucket on bits 20..10 ============
#pragma unroll
    for (int i = 0; i < KPT_S; ++i) {
        if ((int)(keys[i] >> 21) == bucket)
            atomicAdd(&s_hist2[(keys[i] >> 10) & 0x7FFu], 1u);
    }
    __syncthreads();                                           // B3

    {
        const unsigned g0 = s_hist2[2*tid];
        const unsigned g1 = s_hist2[2*tid + 1];
        const unsigned p  = g0 + g1;
        unsigned x = p;
#pragma unroll
        for (int off = 1; off < 64; off <<= 1) {
            unsigned y = __shfl_down(x, off);
            if (lane + off < 64) x += y;
        }
        if (lane == 0) s_wsum[wv] = x;
        __syncthreads();                                       // B4
        unsigned wsuf = 0;
#pragma unroll
        for (int w2 = 0; w2 < 16; ++w2) wsuf += (w2 > wv) ? s_wsum[w2] : 0u;
        const unsigned sufExcl = (x - p) + wsuf;   // in-bucket keys above 2t+1
        const unsigned ku = (unsigned)need;
        const unsigned a1 = sufExcl;
        const unsigned a0 = sufExcl + g1;
        if (a1 < ku && ku <= a1 + g1) { s_bucket = 2*tid + 1; s_above = (int)a1; }
        if (a0 < ku && ku <= a0 + g0) { s_bucket = 2*tid;     s_above = (int)a0; }
        __syncthreads();                                       // B5
    }

    const int bucket2 = s_bucket;       // bits 20..10 of the k-th key
    const int above2  = s_above;        // # in-bucket keys in higher sub-bins
    const int need2   = need - above2;  // rank within 22-bit prefix group
    const unsigned pfx22 = ((unsigned)bucket << 11) | (unsigned)bucket2;

    // ---- collect 22-bit-prefix candidates (expected ~2-30) ----
#pragma unroll
    for (int i = 0; i < KPT_S; ++i) {
        if ((keys[i] >> 10) == pfx22) {
            int slot = atomicAdd(&s_cnt, 1);
            if (slot < CAP)
                s_list[slot] = ((unsigned long long)keys[i] << 32)
                             | (unsigned)(i*BLK_S + tid);
        }
    }
    __syncthreads();                                           // B6

    // ---- exact threshold = need2-th largest among candidates ----
    const int M = s_cnt < CAP ? s_cnt : CAP;
    for (int i = tid; i < M; i += BLK_S) {
        const unsigned ki = (unsigned)(s_list[i] >> 32);
        int gt = 0, eq = 0;
        for (int j = 0; j < M; ++j) {
            const unsigned kj = (unsigned)(s_list[j] >> 32);
            gt += (kj > ki) ? 1 : 0;
            eq += (kj == ki) ? 1 : 0;
        }
        if (gt < need2 && need2 <= gt + eq) {
            s_thr = ki;                 // unique value: duplicate writers agree
            s_cgt = above + above2 + gt;    // global # keys > thr
            s_ceq = eq;                     // global # keys == thr (same pfx)
        }
    }
    __syncthreads();                                           // B7

    const unsigned thr = s_thr;
    const int count_gt = s_cgt;
    const int count_eq = s_ceq;
    const int need_eq  = k - count_gt;          // in [1, count_eq]
    const bool rare    = (count_eq != need_eq);

    // ---- write visible mask over the key buffer; record masked flags ----
    unsigned mbits = 0u;
#pragma unroll
    for (int i = 0; i < KPT_S; ++i) {
        int n = i*BLK_S + tid;
        float v;
        if (keys[i] > thr) {
            v = 1.0f;
        } else if (keys[i] == thr) {
            if (!rare || count_eq > CAP) {
                v = 1.0f;                        // all equals visible
            } else {
                int rk = 0;
                for (int j = 0; j < M; ++j) {
                    unsigned long long e = s_list[j];
                    rk += ((unsigned)(e >> 32) == thr &&
                           (int)(e & 0xFFFFFFFFull) < n) ? 1 : 0;
                }
                v = (rk < need_eq) ? 1.0f : 0.0f; // first need_eq by index
            }
        } else {
            v = 0.0f;
        }
        if (v == 0.0f) mbits |= (1u << i);       // masked
        keybuf[b*N_ + n] = __float_as_uint(v);
    }

    // ---- R9: compact masked token indices over this row's hist region ----
    // (exactly k visible => masked count = N_-k; scan gives per-thread slots)
    const int myc = (int)__popc(mbits);
    int xs = myc;                        // inclusive prefix within wave
#pragma unroll
    for (int off = 1; off < 64; off <<= 1) {
        int y = __shfl_up(xs, off);
        if (lane >= off) xs += y;
    }
    if (lane == 63) s_wsum[wv] = (unsigned)xs;   // wave total
    __syncthreads();                                           // B8
    int wpre = 0;
#pragma unroll
    for (int w2 = 0; w2 < 16; ++w2) wpre += (w2 < wv) ? (int)s_wsum[w2] : 0;
    unsigned off0 = (unsigned)(wpre + xs - myc);
    unsigned* mylist = histlist + (size_t)b*SEG_*NBIN;   // 16384 u32, own region
#pragma unroll
    for (int i = 0; i < KPT_S; ++i) {
        if (mbits & (1u << i))
            mylist[off0++] = (unsigned)(b*N_ + i*BLK_S + tid);  // global token
    }

    if (tid == 0) {
        cnt_out[b] = (unsigned)(N_ - k);         // masked count (exactly k vis)
        float rc = (float)(N_ - k) / (float)N_;  // exact: power-of-2 division
        invrc[b] = 1.0 / (double)rc;
    }
}

// ---------------------------------------------------------------------------
// K2: loss, R9 gather form. 64 blocks per row; each 16-lane group reads one
// masked token's 64 floats (256B contiguous). ~8 fully-active independent
// float4 loads per thread, no vis read, no mask test, uniform per-block
// weight. Same useful bytes as the old conditional form (~65MB) with no
// exec-masked wasted issue slots. R7 LESSON: no __threadfence/device
// atomics in this kernel (killed streaming BW 12.5us -> 96us).
// ---------------------------------------------------------------------------
__global__ __launch_bounds__(BLK, 1) void loss_kernel(
    const float4* __restrict__ s4,       // score as float4[8M]
    const unsigned* __restrict__ list,   // [B_][N_] masked global-token ids
    const unsigned* __restrict__ cnt,    // [B_] masked counts
    const double* __restrict__ invrc,    // ws[0..31]
    double*       __restrict__ partial)  // ws[32 .. 32+LOSS_BLOCKS)
{
    const int tid = threadIdx.x;
    const int g   = tid >> 4;            // group 0..15 (one token each)
    const int l   = tid & 15;            // float4 lane within token
    const int bid = blockIdx.x;
    const int b   = bid >> 6;            // row
    const int j0  = bid & 63;            // block-within-row
    const int m   = (int)cnt[b];
    const unsigned* ml = list + (size_t)b*N_;
    const double w = invrc[b];

    // prefetch up to 16 list entries (independent; invalid -> sentinel)
    unsigned gt[16];
#pragma unroll
    for (int s = 0; s < 16; ++s) {
        int slot = (s*64 + j0)*16 + g;
        gt[s] = (slot < m) ? ml[slot] : 0xFFFFFFFFu;
    }

    double a = 0.0;
#pragma unroll
    for (int s = 0; s < 16; ++s) {
        if (gt[s] != 0xFFFFFFFFu) {
            float4 x = s4[(size_t)gt[s]*16 + l];
            float  sv = (x.x + x.y) + (x.z + x.w);   // float sum, then double
            a += (double)sv * w;
        }
    }

    for (int off = 32; off > 0; off >>= 1) a += __shfl_down(a, off);
    __shared__ double s_a[4];
    if ((tid & 63) == 0) s_a[tid >> 6] = a;
    __syncthreads();
    if (tid == 0) partial[bid] = s_a[0] + s_a[1] + s_a[2] + s_a[3];
}

// ---------------------------------------------------------------------------
// K3: sum 2048 partials, finalize loss = acc / 2^25
// ---------------------------------------------------------------------------
__global__ __launch_bounds__(BLK, 1) void finalize_kernel(
    const double* __restrict__ partial,
    float* __restrict__ out)
{
    const int tid = threadIdx.x;
    double t = 0.0;
    for (int i = tid; i < LOSS_BLOCKS; i += BLK) t += partial[i];
    for (int off = 32; off > 0; off >>= 1) t += __shfl_down(t, off);
    __shared__ double s_a[4];
    if ((tid & 63) == 0) s_a[tid >> 6] = t;
    __syncthreads();
    if (tid == 0)
        out[0] = (float)((s_a[0] + s_a[1] + s_a[2] + s_a[3]) / 33554432.0);
}

extern "C" void kernel_launch(void* const* d_in, const int* in_sizes, int n_in,
                              void* d_out, int out_size, void* d_ws, size_t ws_size,
                              hipStream_t stream) {
    const float* u_g    = (const float*)d_in[0];
    const float* logp_t = (const float*)d_in[1];
    const float* logp_h = (const float*)d_in[2];
    const float* logp_w = (const float*)d_in[3];
    const float* u_k    = (const float*)d_in[4];
    const float* score  = (const float*)d_in[5];

    float*  out     = (float*)d_out;     // [0]=loss, [1..B*N]=visible (0/1)
    double* wsd     = (double*)d_ws;
    double*   invrc   = wsd;                          // 32 doubles
    double*   partial = wsd + B_;                     // 2048 doubles
    unsigned* cntbuf  = (unsigned*)(wsd + B_ + LOSS_BLOCKS);      // 32 u32
    unsigned* histbuf = (unsigned*)(wsd + B_ + LOSS_BLOCKS + 16); // [256][2048] u32
    unsigned* keybuf  = (unsigned*)(out + 1);         // keys, then mask bits

    select_a_kernel<<<B_*SEG_, BLK_S, 0, stream>>>(u_g, logp_t, logp_h, logp_w,
                                                   keybuf, histbuf);
    select_b_kernel<<<B_, BLK_S, 0, stream>>>(keybuf, histbuf, u_k, invrc,
                                              cntbuf);
    loss_kernel<<<LOSS_BLOCKS, BLK, 0, stream>>>((const float4*)score, histbuf,
                                                 cntbuf, invrc, partial);
    finalize_kernel<<<1, BLK, 0, stream>>>(partial, out);
}